// Round 15
// baseline (246.063 us; speedup 1.0000x reference)
//
#include <hip/hip_runtime.h>
#include <hip/hip_bf16.h>
#include <math.h>

typedef unsigned int u32;
typedef short bf16x8 __attribute__((ext_vector_type(8)));
typedef float f32x4 __attribute__((ext_vector_type(4)));
typedef u32 u32x4 __attribute__((ext_vector_type(4)));

__device__ __forceinline__ float bf2f(short s) {
    u32 u = ((u32)(unsigned short)s) << 16;
    return __builtin_bit_cast(float, u);
}
__device__ __forceinline__ short f2bf(float f) {
    u32 u = __builtin_bit_cast(u32, f);
    u32 r = u + 0x7fffu + ((u >> 16) & 1u);
    return (short)(r >> 16);
}
__device__ __forceinline__ float fast_log2(float x) {
    float r; asm volatile("v_log_f32 %0, %1" : "=v"(r) : "v"(x)); return r;
}
__device__ __forceinline__ float fast_exp2(float x) {
    float r; asm volatile("v_exp_f32 %0, %1" : "=v"(r) : "v"(x)); return r;
}
// async global->LDS, 16B per lane; lds base must be wave-uniform
__device__ __forceinline__ void gload_lds16(const short* g, short* lds) {
    __builtin_amdgcn_global_load_lds(
        (const __attribute__((address_space(1))) u32*)g,
        (__attribute__((address_space(3))) u32*)lds, 16, 0, 0);
}
__device__ __forceinline__ bf16x8 stripsign(bf16x8 v) {
    u32x4 u = __builtin_bit_cast(u32x4, v);
    u &= 0x7fff7fffu;
    return __builtin_bit_cast(bf16x8, u);
}

// All pointers a gemm epilogue might need
struct P {
    const float* bcat; const float* pcol;
    short* qa; short* ka;           // SIGNED magnitude bf16: copysign(|v|^p, v)
    short* vt; short* kvt;
    const float* dsb; const float* dcb; const float* Ws; const float* Wc;
    short* Y; float* out;
};

// ---------------- pack weights: WcatT [2048][512] bf16 (round-6 layout) ----------------
__global__ void k_pack(const float* __restrict__ Wq, const float* __restrict__ Wk,
                       const float* __restrict__ Wvs, const float* __restrict__ Wvc,
                       const float* __restrict__ Wp,
                       const float* __restrict__ bq, const float* __restrict__ bk,
                       const float* __restrict__ bvs, const float* __restrict__ bvc,
                       const float* __restrict__ bp, const float* __restrict__ power,
                       short* __restrict__ WcatT, float* __restrict__ bcat, float* __restrict__ pcol)
{
    int i = blockIdx.x * 256 + threadIdx.x;
    int r = i >> 9, k = i & 511;
    float w;
    if (r < 512)       w = Wq[k * 512 + r];
    else if (r < 1024) w = Wk[k * 512 + (r - 512)];
    else if (r < 1536) {
        int rr = r - 1024; int h = rr >> 8; int d = rr & 255;
        w = (d < 128) ? Wvs[k * 256 + h * 128 + d] : Wvc[k * 256 + h * 128 + (d - 128)];
    } else             w = Wp[k * 512 + (r - 1536)];
    WcatT[i] = f2bf(w);

    if (i < 2048) {
        float bb;
        if (i < 512)       bb = bq[i];
        else if (i < 1024) bb = bk[i - 512];
        else if (i < 1536) {
            int rr = i - 1024; int h = rr >> 8; int d = rr & 255;
            bb = (d < 128) ? bvs[h * 128 + d] : bvc[h * 128 + (d - 128)];
        } else             bb = bp[i - 1536];
        bcat[i] = bb;
    }
    if (i < 512) pcol[i] = 1.0f + 3.0f / (1.0f + expf(-power[i]));
}

// ---------------- cast x -> bf16 ----------------
__global__ void k_cast(const float* __restrict__ x, short* __restrict__ xb)
{
    int i = blockIdx.x * 256 + threadIdx.x;
    float4 v = ((const float4*)x)[i];
    short4 s;
    s.x = f2bf(v.x); s.y = f2bf(v.y); s.z = f2bf(v.z); s.w = f2bf(v.w);
    ((short4*)xb)[i] = s;
}

// ---------------- per-row sums of k_pos / k_neg ----------------
__global__ void k_ksum(const short* __restrict__ ka,
                       float* __restrict__ kpsum, float* __restrict__ knsum)
{
    int gid = blockIdx.x * 256 + threadIdx.x;
    int gw = gid >> 6;
    int lane = gid & 63;
    short4 a4 = ((const short4*)(ka + ((size_t)gw << 8)))[lane];
    short aa[4] = {a4.x, a4.y, a4.z, a4.w};
    float sp = 0.f, sn = 0.f;
#pragma unroll
    for (int j = 0; j < 4; ++j) {
        float a = fabsf(bf2f(aa[j]));
        if (((unsigned short)aa[j] >> 15) == 0) sp += a; else sn += a;
    }
#pragma unroll
    for (int m = 1; m < 64; m <<= 1) { sp += __shfl_xor(sp, m, 64); sn += __shfl_xor(sn, m, 64); }
    if (lane == 0) { kpsum[gw] = sp; knsum[gw] = sn; }
}

// ---------------- denominators ----------------
__global__ void k_denom(const short* __restrict__ qa,
                        const float* __restrict__ kpsum, const float* __restrict__ knsum,
                        float* __restrict__ dsb, float* __restrict__ dcb)
{
    int gid = blockIdx.x * 256 + threadIdx.x;
    int gw = gid >> 6;
    int lane = gid & 63;
    int bhl = gw >> 8;
    short4 q4 = ((const short4*)(qa + ((size_t)gw << 8)))[lane];
    float4 kp4 = ((const float4*)(kpsum + ((size_t)bhl << 8)))[lane];
    float4 kn4 = ((const float4*)(knsum + ((size_t)bhl << 8)))[lane];
    short qq[4] = {q4.x, q4.y, q4.z, q4.w};
    float kp[4] = {kp4.x, kp4.y, kp4.z, kp4.w};
    float kn[4] = {kn4.x, kn4.y, kn4.z, kn4.w};
    float ss = 0.f, sc = 0.f;
#pragma unroll
    for (int j = 0; j < 4; ++j) {
        float a = fabsf(bf2f(qq[j]));
        if (((unsigned short)qq[j] >> 15) == 0) { ss += a * kp[j]; sc += a * kn[j]; }
        else                                    { ss += a * kn[j]; sc += a * kp[j]; }
    }
#pragma unroll
    for (int m = 1; m < 64; m <<= 1) { ss += __shfl_xor(ss, m, 64); sc += __shfl_xor(sc, m, 64); }
    if (lane == 0) { dsb[gw] = ss; dcb[gw] = sc; }
}

#define MODE_QK  0
#define MODE_VT  1
#define MODE_KV  2
#define MODE_CTX 3
#define MODE_OUT 4

// ======== 256x256 8-phase GEMM (K=512 fixed): QK / VT / OUT ========
// C[m][n] = sum_k A[m][k]*B[n][k]; 8 waves (2M x 4N); dbuf LDS; raw s_barrier
// (no implicit vmcnt drain); stage row-halves of tile kt+1 during group kt.
template <int MODE>
__launch_bounds__(512, 2)
__global__ void gemm8(const short* __restrict__ Ag, const short* __restrict__ Bg,
                      int tilesN, P p)
{
    __shared__ __align__(16) short sm[65536];   // 2 x (A[256][64] + B[256][64]) = 128 KiB

    const int nwg = gridDim.x;
    const int s0 = blockIdx.x;
    const int cpx = nwg >> 3;
    const int lin = (s0 & 7) * cpx + (s0 >> 3);
    const int tm = lin / tilesN, tn = lin % tilesN;

    const int t = threadIdx.x;
    const int lane = t & 63;
    const int w = t >> 6;           // 0..7
    const int wr = w >> 2;          // 0..1 -> rows wr*128..+127
    const int wc = w & 3;           // 0..3 -> cols wc*64..+63

    const short* A = Ag + (size_t)tm * 256 * 512;
    const short* B = Bg + (size_t)tn * 256 * 512;

    // stage rows [h*128, +128) x cols [kt*64, +64) of panel G into LDS tile
    // (pre-swizzled global source, linear LDS dest -> read-side XOR works)
    auto stage_half = [&](const short* G, short* tile, int h, int kt) {
#pragma unroll
        for (int q = 0; q < 2; ++q) {
            int u = q * 512 + t;            // granule 0..1023 of this half
            int lr = u >> 3, pp = u & 7;
            int g = pp ^ (lr & 7);
            gload_lds16(G + (size_t)(h * 128 + lr) * 512 + kt * 64 + g * 8,
                        tile + h * 8192 + (q * 512 + w * 64) * 8);
        }
    };
    auto lda = [&](bf16x8* a, const short* At, int kk, int mh) {
#pragma unroll
        for (int m2 = 0; m2 < 4; ++m2) {
            int row = wr * 128 + mh * 64 + m2 * 16 + (lane & 15);
            int ch = kk * 4 + (lane >> 4);
            a[m2] = *(const bf16x8*)(At + row * 64 + ((ch ^ (row & 7)) << 3));
        }
    };
    auto ldb = [&](bf16x8* b, const short* Bt, int kk) {
#pragma unroll
        for (int nf = 0; nf < 4; ++nf) {
            int row = wc * 64 + nf * 16 + (lane & 15);
            int ch = kk * 4 + (lane >> 4);
            b[nf] = *(const bf16x8*)(Bt + row * 64 + ((ch ^ (row & 7)) << 3));
        }
    };

    f32x4 acc[8][4];
#pragma unroll
    for (int i = 0; i < 8; ++i)
#pragma unroll
        for (int j = 0; j < 4; ++j) acc[i][j] = 0.f;

    // prologue: tile 0 -> buf0
    stage_half(A, sm, 0, 0); stage_half(A, sm, 1, 0);
    stage_half(B, sm + 16384, 0, 0); stage_half(B, sm + 16384, 1, 0);
    asm volatile("s_waitcnt vmcnt(0)" ::: "memory");
    __builtin_amdgcn_sched_barrier(0);
    __builtin_amdgcn_s_barrier();

    for (int kt = 0; kt < 8; ++kt) {
        const short* At = sm + (kt & 1) * 32768;
        const short* Bt = At + 16384;
        short* An = sm + ((kt + 1) & 1) * 32768;
        short* Bn = An + 16384;
        const bool pf = (kt + 1) < 8;
        bf16x8 a[4], b[4];

        // ---- P1: (kk0, mh0) + b load; stage A(kt+1) h0
        lda(a, At, 0, 0); ldb(b, Bt, 0);
        if (pf) stage_half(A, An, 0, kt + 1);
        __builtin_amdgcn_s_barrier();
        asm volatile("s_waitcnt lgkmcnt(0)" ::: "memory");
        __builtin_amdgcn_sched_barrier(0);
        __builtin_amdgcn_s_setprio(1);
#pragma unroll
        for (int m2 = 0; m2 < 4; ++m2)
#pragma unroll
            for (int nf = 0; nf < 4; ++nf)
                acc[m2][nf] = __builtin_amdgcn_mfma_f32_16x16x32_bf16(a[m2], b[nf], acc[m2][nf], 0, 0, 0);
        __builtin_amdgcn_s_setprio(0);
        __builtin_amdgcn_s_barrier();

        // ---- P2: (kk0, mh1), b reused; stage B(kt+1) h0
        lda(a, At, 0, 1);
        if (pf) stage_half(B, Bn, 0, kt + 1);
        __builtin_amdgcn_s_barrier();
        asm volatile("s_waitcnt lgkmcnt(0)" ::: "memory");
        __builtin_amdgcn_sched_barrier(0);
        __builtin_amdgcn_s_setprio(1);
#pragma unroll
        for (int m2 = 0; m2 < 4; ++m2)
#pragma unroll
            for (int nf = 0; nf < 4; ++nf)
                acc[4 + m2][nf] = __builtin_amdgcn_mfma_f32_16x16x32_bf16(a[m2], b[nf], acc[4 + m2][nf], 0, 0, 0);
        __builtin_amdgcn_s_setprio(0);
        __builtin_amdgcn_s_barrier();

        // ---- P3: (kk1, mh0) + b load; stage A(kt+1) h1
        lda(a, At, 1, 0); ldb(b, Bt, 1);
        if (pf) stage_half(A, An, 1, kt + 1);
        __builtin_amdgcn_s_barrier();
        asm volatile("s_waitcnt lgkmcnt(0)" ::: "memory");
        __builtin_amdgcn_sched_barrier(0);
        __builtin_amdgcn_s_setprio(1);
#pragma unroll
        for (int m2 = 0; m2 < 4; ++m2)
#pragma unroll
            for (int nf = 0; nf < 4; ++nf)
                acc[m2][nf] = __builtin_amdgcn_mfma_f32_16x16x32_bf16(a[m2], b[nf], acc[m2][nf], 0, 0, 0);
        __builtin_amdgcn_s_setprio(0);
        __builtin_amdgcn_s_barrier();

        // ---- P4: (kk1, mh1), b reused; stage B(kt+1) h1; boundary drain
        lda(a, At, 1, 1);
        if (pf) stage_half(B, Bn, 1, kt + 1);
        __builtin_amdgcn_s_barrier();
        asm volatile("s_waitcnt lgkmcnt(0)" ::: "memory");
        __builtin_amdgcn_sched_barrier(0);
        __builtin_amdgcn_s_setprio(1);
#pragma unroll
        for (int m2 = 0; m2 < 4; ++m2)
#pragma unroll
            for (int nf = 0; nf < 4; ++nf)
                acc[4 + m2][nf] = __builtin_amdgcn_mfma_f32_16x16x32_bf16(a[m2], b[nf], acc[4 + m2][nf], 0, 0, 0);
        __builtin_amdgcn_s_setprio(0);
        asm volatile("s_waitcnt vmcnt(0)" ::: "memory");   // tile kt+1 fully landed
        __builtin_amdgcn_sched_barrier(0);
        __builtin_amdgcn_s_barrier();
    }

    // -------- epilogue (LDS-staged coalesced stores, r12-proven mechanism) --------
    if (MODE == MODE_QK || MODE == MODE_VT) {
#pragma unroll
        for (int mf = 0; mf < 8; ++mf) {
#pragma unroll
            for (int nf = 0; nf < 4; ++nf) {
#pragma unroll
                for (int r = 0; r < 4; ++r) {
                    int lrow = wr * 128 + mf * 16 + (lane >> 4) * 4 + r;
                    int lcol = wc * 64 + nf * 16 + (lane & 15);
                    float v = acc[mf][nf][r];
                    short sv;
                    if (MODE == MODE_QK) {
                        int col_g = tn * 256 + lcol;
                        v += p.bcat[col_g];
                        float pw = p.pcol[col_g & 511];
                        float aa = (v != 0.0f) ? fast_exp2(pw * fast_log2(fabsf(v))) : 0.0f;
                        unsigned short sa = (unsigned short)f2bf(aa);
                        sa |= (unsigned short)((__builtin_bit_cast(u32, v) >> 16) & 0x8000u);
                        sv = (short)sa;
                    } else { // MODE_VT: rows are d (Wv index), cols are n
                        v += p.bcat[1024 + tm * 256 + lrow];
                        sv = f2bf(v);
                    }
                    int g = lcol >> 3;
                    sm[lrow * 256 + ((g ^ (lrow & 7)) << 3) + (lcol & 7)] = sv;
                }
            }
        }
        __syncthreads();
#pragma unroll
        for (int i = 0; i < 16; ++i) {
            int slot = i * 512 + t;             // 8192 granules
            int lrow = slot >> 5;
            int g = slot & 31;
            bf16x8 val = *(const bf16x8*)&sm[lrow * 256 + ((g ^ (lrow & 7)) << 3)];
            int col0 = tn * 256 + g * 8;
            if (MODE == MODE_QK) {
                int row_g = tm * 256 + lrow;
                int bl = row_g >> 8, n = row_g & 255;
                int h = (col0 >> 8) & 1;
                short* dst = (col0 < 512) ? p.qa : p.ka;
                *(bf16x8*)(dst + (((size_t)((bl * 2 + h) * 256 + n)) << 8) + (col0 & 255)) = val;
            } else {
                int d_g = tm * 256 + lrow;
                int h = d_g >> 8, d = d_g & 255;
                int bl = col0 >> 8, n0 = col0 & 255;
                *(bf16x8*)(p.vt + (((size_t)((bl * 2 + h) * 256 + d)) << 8) + n0) = val;
            }
        }
    } else { // MODE_OUT: fp32, two 128-row passes
        float* smf = (float*)sm;                // 32768 floats = 128x256
#pragma unroll
        for (int half = 0; half < 2; ++half) {
            if (wr == half) {
#pragma unroll
                for (int mf = 0; mf < 8; ++mf) {
#pragma unroll
                    for (int nf = 0; nf < 4; ++nf) {
#pragma unroll
                        for (int r = 0; r < 4; ++r) {
                            int lrow = mf * 16 + (lane >> 4) * 4 + r;   // 0..127
                            int lcol = wc * 64 + nf * 16 + (lane & 15);
                            float v = acc[mf][nf][r] + p.bcat[1536 + tn * 256 + lcol];
                            int g = lcol >> 2;
                            smf[lrow * 256 + ((g ^ (lrow & 7)) << 2) + (lcol & 3)] = v;
                        }
                    }
                }
            }
            __syncthreads();
#pragma unroll
            for (int i = 0; i < 16; ++i) {
                int slot = i * 512 + t;         // 8192 float4 slots
                int lrow = slot >> 6;           // 0..127
                int g = slot & 63;
                float4 val = *(const float4*)&smf[lrow * 256 + ((g ^ (lrow & 7)) << 2)];
                int row_g = tm * 256 + half * 128 + lrow;
                *(float4*)(p.out + ((size_t)row_g << 9) + tn * 256 + g * 4) = val;
            }
            __syncthreads();
        }
    }
}

// ---------------- NT GEMM 128x128 (proven): KV / CTX ----------------
template <int MODE>
__launch_bounds__(256, 4)
__global__ void gemm_nt(const short* __restrict__ Ag, const short* __restrict__ Bg,
                        int K, int tilesN, P p)
{
    __shared__ __align__(16) short sm[16384];
    short* As = sm;
    short* Bs = sm + 8192;

    const int nwg = gridDim.x * gridDim.y;
    const int s = blockIdx.y * gridDim.x + blockIdx.x;
    const int cpx = nwg >> 3;
    const int lin = (s & 7) * cpx + (s >> 3);

    const int bhl = lin >> 2;
    const int rem = lin & 3;
    const int tm = rem / tilesN, tn = rem % tilesN;

    const short* A = Ag + ((size_t)bhl << 16);
    const short* B = Bg + ((size_t)bhl << 16);
    constexpr bool stripA = (MODE == MODE_CTX);
    constexpr bool stripB = (MODE == MODE_KV);

    const int t = threadIdx.x;
    const int lane = t & 63;
    const int w = t >> 6;
    const int wr = w >> 1, wc = w & 1;

    f32x4 acc[4][4];
#pragma unroll
    for (int i = 0; i < 4; ++i)
#pragma unroll
        for (int j = 0; j < 4; ++j) acc[i][j] = 0.f;

    const int nkt = K >> 6;
    for (int kt = 0; kt < nkt; ++kt) {
#pragma unroll
        for (int q4i = 0; q4i < 4; ++q4i) {
            int seg = w * 4 + q4i;
            int r = seg * 8 + (lane >> 3);
            int c = (lane & 7) ^ (r & 7);
            gload_lds16(A + (size_t)(tm * 128 + r) * K + kt * 64 + c * 8, &As[seg * 512]);
            gload_lds16(B + (size_t)(tn * 128 + r) * K + kt * 64 + c * 8, &Bs[seg * 512]);
        }
        __syncthreads();
#pragma unroll
        for (int kk = 0; kk < 2; ++kk) {
            bf16x8 af[4], bfr[4];
#pragma unroll
            for (int mt = 0; mt < 4; ++mt) {
                int row = wr * 64 + mt * 16 + (lane & 15);
                int ch = kk * 4 + (lane >> 4);
                af[mt] = *(const bf16x8*)(&As[row * 64 + ((ch ^ (row & 7)) << 3)]);
                if constexpr (stripA) af[mt] = stripsign(af[mt]);
            }
#pragma unroll
            for (int nt = 0; nt < 4; ++nt) {
                int row = wc * 64 + nt * 16 + (lane & 15);
                int ch = kk * 4 + (lane >> 4);
                bfr[nt] = *(const bf16x8*)(&Bs[row * 64 + ((ch ^ (row & 7)) << 3)]);
                if constexpr (stripB) bfr[nt] = stripsign(bfr[nt]);
            }
#pragma unroll
            for (int mt = 0; mt < 4; ++mt)
#pragma unroll
                for (int nt = 0; nt < 4; ++nt)
                    acc[mt][nt] = __builtin_amdgcn_mfma_f32_16x16x32_bf16(af[mt], bfr[nt], acc[mt][nt], 0, 0, 0);
        }
        __syncthreads();
    }

    // LDS-staged coalesced bf16 stores
#pragma unroll
    for (int mt = 0; mt < 4; ++mt) {
#pragma unroll
        for (int nt = 0; nt < 4; ++nt) {
#pragma unroll
            for (int r = 0; r < 4; ++r) {
                int lrow = wr * 64 + mt * 16 + (lane >> 4) * 4 + r;
                int lcol = wc * 64 + nt * 16 + (lane & 15);
                float v = acc[mt][nt][r];
                short sv;
                if (MODE == MODE_KV) {
                    sv = f2bf(v);
                } else { // MODE_CTX
                    int n = tm * 128 + lrow, d = tn * 128 + lcol;
                    float den = ((d < 128) ? p.dsb : p.dcb)[bhl * 256 + n] + 1e-6f;
                    float wgt = (d < 128) ? p.Ws[n * 128 + d] : p.Wc[n * 128 + (d - 128)];
                    sv = f2bf(v / den * wgt);
                }
                int g = lcol >> 3;
                sm[lrow * 128 + ((g ^ (lrow & 7)) << 3) + (lcol & 7)] = sv;
            }
        }
    }
    __syncthreads();
#pragma unroll
    for (int i = 0; i < 8; ++i) {
        int slot = i * 256 + t;
        int lrow = slot >> 4;
        int g = slot & 15;
        bf16x8 val = *(const bf16x8*)&sm[lrow * 128 + ((g ^ (lrow & 7)) << 3)];
        int row = tm * 128 + lrow;
        int col0 = tn * 128 + g * 8;
        if (MODE == MODE_KV) {
            *(bf16x8*)(p.kvt + ((size_t)bhl << 16) + (row << 8) + col0) = val;
        } else {
            int bl = bhl >> 1, h = bhl & 1;
            *(bf16x8*)(p.Y + ((size_t)(bl * 256 + row) << 9) + h * 256 + col0) = val;
        }
    }
}

extern "C" void kernel_launch(void* const* d_in, const int* in_sizes, int n_in,
                              void* d_out, int out_size, void* d_ws, size_t ws_size,
                              hipStream_t stream)
{
    const float* x     = (const float*)d_in[0];
    const float* Wq    = (const float*)d_in[1];
    const float* bq    = (const float*)d_in[2];
    const float* Wk    = (const float*)d_in[3];
    const float* bk    = (const float*)d_in[4];
    const float* Wvs   = (const float*)d_in[5];
    const float* bvs   = (const float*)d_in[6];
    const float* Wvc   = (const float*)d_in[7];
    const float* bvc   = (const float*)d_in[8];
    const float* power = (const float*)d_in[9];
    const float* Ws    = (const float*)d_in[10];
    const float* Wc    = (const float*)d_in[11];
    const float* Wp    = (const float*)d_in[12];
    const float* bp    = (const float*)d_in[13];
    (void)in_sizes; (void)n_in; (void)out_size; (void)ws_size;

    char* ws = (char*)d_ws;
    size_t off = 0;
    auto alloc = [&](size_t bytes) { void* pp = ws + off; off += (bytes + 255) & ~(size_t)255; return pp; };
    short* Wcat = (short*)alloc(2097152);           // [2048][512] bf16
    float* bcat = (float*)alloc(8192);
    float* pcol = (float*)alloc(2048);
    short* xb   = (short*)alloc(33554432);          // [32768][512] bf16; reused as Y by CTX
    short* qa   = (short*)alloc(33554432);          // [256 bhl][256 n][256] signed bf16
    short* ka   = (short*)alloc(33554432);
    short* vt   = (short*)alloc(33554432);          // [256 bhl][256 d][256 n]
    short* kvt  = (short*)alloc(33554432);
    float* kpsum= (float*)alloc(262144);
    float* knsum= (float*)alloc(262144);
    float* dsb  = (float*)alloc(262144);
    float* dcb  = (float*)alloc(262144);

    P p{};
    p.bcat = bcat; p.pcol = pcol;
    p.qa = qa; p.ka = ka;
    p.vt = vt; p.kvt = kvt;
    p.dsb = dsb; p.dcb = dcb; p.Ws = Ws; p.Wc = Wc;
    p.Y = xb; p.out = nullptr;                      // Y overwrites xb (safe: CTX after VT)

    k_pack<<<4096, 256, 0, stream>>>(Wq, Wk, Wvs, Wvc, Wp, bq, bk, bvs, bvc, bp, power, Wcat, bcat, pcol);

    k_cast<<<16384, 256, 0, stream>>>(x, xb);

    // Q/K projection + power transform: M=32768, N=1024 (256^2 8-phase)
    gemm8<MODE_QK><<<512, 512, 0, stream>>>(xb, Wcat, 4, p);

    // V projection, produced transposed: A=WvT (512 rows), B=xb
    gemm8<MODE_VT><<<256, 512, 0, stream>>>(Wcat + 1024 * 512, xb, 128, p);

    // kvT[bhl][d][n] = sum_j vt[d][j] * |ka[n][j]|
    gemm_nt<MODE_KV><<<dim3(4, 256), 256, 0, stream>>>(vt, ka, 256, 2, p);

    k_ksum<<<16384, 256, 0, stream>>>(ka, kpsum, knsum);
    k_denom<<<16384, 256, 0, stream>>>(qa, kpsum, knsum, dsb, dcb);

    // ctx[n][d] = sum_i |qa[n][i]|*kvT[d][i] -> Y (=xb)
    gemm_nt<MODE_CTX><<<dim3(4, 256), 256, 0, stream>>>(qa, kvt, 256, 2, p);

    // out = Y @ Wp + bp (fp32): M=32768, N=512 (256^2 8-phase)
    P po = p;
    po.out = (float*)d_out;
    gemm8<MODE_OUT><<<256, 512, 0, stream>>>(xb, Wcat + 1536 * 512, 2, po);
}

// Round 16
// 217.826 us; speedup vs baseline: 1.1296x; 1.1296x over previous
//
#include <hip/hip_runtime.h>
#include <hip/hip_bf16.h>
#include <math.h>

typedef unsigned int u32;
typedef short bf16x8 __attribute__((ext_vector_type(8)));
typedef float f32x4 __attribute__((ext_vector_type(4)));
typedef u32 u32x4 __attribute__((ext_vector_type(4)));

__device__ __forceinline__ float bf2f(short s) {
    u32 u = ((u32)(unsigned short)s) << 16;
    return __builtin_bit_cast(float, u);
}
__device__ __forceinline__ short f2bf(float f) {
    u32 u = __builtin_bit_cast(u32, f);
    u32 r = u + 0x7fffu + ((u >> 16) & 1u);
    return (short)(r >> 16);
}
__device__ __forceinline__ float fast_log2(float x) {
    float r; asm volatile("v_log_f32 %0, %1" : "=v"(r) : "v"(x)); return r;
}
__device__ __forceinline__ float fast_exp2(float x) {
    float r; asm volatile("v_exp_f32 %0, %1" : "=v"(r) : "v"(x)); return r;
}
// async global->LDS, 16B per lane; lds base must be wave-uniform
__device__ __forceinline__ void gload_lds16(const short* g, short* lds) {
    __builtin_amdgcn_global_load_lds(
        (const __attribute__((address_space(1))) u32*)g,
        (__attribute__((address_space(3))) u32*)lds, 16, 0, 0);
}
__device__ __forceinline__ bf16x8 stripsign(bf16x8 v) {
    u32x4 u = __builtin_bit_cast(u32x4, v);
    u &= 0x7fff7fffu;
    return __builtin_bit_cast(bf16x8, u);
}

// All pointers a gemm epilogue might need
struct P {
    const float* bcat; const float* pcol;
    short* qa; short* ka;           // SIGNED magnitude bf16: copysign(|v|^p, v)
    short* vt; short* kvt;
    const float* dsb; const float* dcb; const float* Ws; const float* Wc;
    short* Y; float* out;
};

#define MODE_QK  0
#define MODE_VT  1
#define MODE_KV  2
#define MODE_CTX 3
#define MODE_OUT 4

// ---------------- NT GEMM body (r14-proven, byte-identical logic) ----------------
template <int MODE>
__device__ __forceinline__ void gemm_body(short* __restrict__ sm, int lin,
                                          const short* __restrict__ Ag, const short* __restrict__ Bg,
                                          int K, int tilesN, const P& p)
{
    short* As = sm;
    short* Bs = sm + 8192;

    int tm, tn, bhl;
    if (MODE == MODE_KV || MODE == MODE_CTX) {
        bhl = lin >> 2;
        int rem = lin & 3;
        tm = rem / tilesN; tn = rem % tilesN;
    } else {
        bhl = 0;
        tm = lin / tilesN; tn = lin % tilesN;
    }

    const short* A = Ag;
    const short* B = Bg;
    if (MODE == MODE_KV || MODE == MODE_CTX) {
        A += (size_t)bhl << 16;
        B += (size_t)bhl << 16;
    }
    constexpr bool stripA = (MODE == MODE_CTX);
    constexpr bool stripB = (MODE == MODE_KV);

    const int t = threadIdx.x;
    const int lane = t & 63;
    const int w = t >> 6;
    const int wr = w >> 1, wc = w & 1;

    f32x4 acc[4][4];
#pragma unroll
    for (int i = 0; i < 4; ++i)
#pragma unroll
        for (int j = 0; j < 4; ++j) acc[i][j] = 0.f;

    const int nkt = K >> 6;
    for (int kt = 0; kt < nkt; ++kt) {
#pragma unroll
        for (int q4i = 0; q4i < 4; ++q4i) {
            int seg = w * 4 + q4i;
            int r = seg * 8 + (lane >> 3);
            int c = (lane & 7) ^ (r & 7);
            gload_lds16(A + (size_t)(tm * 128 + r) * K + kt * 64 + c * 8, &As[seg * 512]);
            gload_lds16(B + (size_t)(tn * 128 + r) * K + kt * 64 + c * 8, &Bs[seg * 512]);
        }
        __syncthreads();
#pragma unroll
        for (int kk = 0; kk < 2; ++kk) {
            bf16x8 af[4], bfr[4];
#pragma unroll
            for (int mt = 0; mt < 4; ++mt) {
                int row = wr * 64 + mt * 16 + (lane & 15);
                int ch = kk * 4 + (lane >> 4);
                af[mt] = *(const bf16x8*)(&As[row * 64 + ((ch ^ (row & 7)) << 3)]);
                if constexpr (stripA) af[mt] = stripsign(af[mt]);
            }
#pragma unroll
            for (int nt = 0; nt < 4; ++nt) {
                int row = wc * 64 + nt * 16 + (lane & 15);
                int ch = kk * 4 + (lane >> 4);
                bfr[nt] = *(const bf16x8*)(&Bs[row * 64 + ((ch ^ (row & 7)) << 3)]);
                if constexpr (stripB) bfr[nt] = stripsign(bfr[nt]);
            }
#pragma unroll
            for (int mt = 0; mt < 4; ++mt)
#pragma unroll
                for (int nt = 0; nt < 4; ++nt)
                    acc[mt][nt] = __builtin_amdgcn_mfma_f32_16x16x32_bf16(af[mt], bfr[nt], acc[mt][nt], 0, 0, 0);
        }
        __syncthreads();
    }

    // -------- epilogue --------
    if (MODE == MODE_QK || MODE == MODE_VT) {
#pragma unroll
        for (int mt = 0; mt < 4; ++mt) {
#pragma unroll
            for (int nt = 0; nt < 4; ++nt) {
#pragma unroll
                for (int r = 0; r < 4; ++r) {
                    int lrow = wr * 64 + mt * 16 + (lane >> 4) * 4 + r;
                    int lcol = wc * 64 + nt * 16 + (lane & 15);
                    float v = acc[mt][nt][r];
                    short sv;
                    if (MODE == MODE_QK) {
                        int col_g = tn * 128 + lcol;
                        v += p.bcat[col_g];
                        float pw = p.pcol[col_g & 511];
                        float a = (v != 0.0f) ? fast_exp2(pw * fast_log2(fabsf(v))) : 0.0f;
                        unsigned short sa = (unsigned short)f2bf(a);
                        sa |= (unsigned short)((__builtin_bit_cast(u32, v) >> 16) & 0x8000u);
                        sv = (short)sa;
                    } else { // MODE_VT
                        v += p.bcat[1024 + tm * 128 + lrow];
                        sv = f2bf(v);
                    }
                    int g = lcol >> 3;
                    sm[lrow * 128 + ((g ^ (lrow & 7)) << 3) + (lcol & 7)] = sv;
                }
            }
        }
        __syncthreads();
#pragma unroll
        for (int i = 0; i < 8; ++i) {
            int slot = i * 256 + t;
            int lrow = slot >> 4;
            int g = slot & 15;
            bf16x8 val = *(const bf16x8*)&sm[lrow * 128 + ((g ^ (lrow & 7)) << 3)];
            if (MODE == MODE_QK) {
                int row_g = tm * 128 + lrow;
                int col0 = tn * 128 + g * 8;
                int bl = row_g >> 8, n = row_g & 255;
                int h = (col0 >> 8) & 1;
                short* dst = (col0 < 512) ? p.qa : p.ka;
                *(bf16x8*)(dst + (((size_t)((bl * 2 + h) * 256 + n)) << 8) + (col0 & 255)) = val;
            } else {
                int d_g = tm * 128 + lrow;
                int col0 = tn * 128 + g * 8;
                int h = d_g >> 8, d = d_g & 255;
                int bl = col0 >> 8, n0 = col0 & 255;
                *(bf16x8*)(p.vt + (((size_t)((bl * 2 + h) * 256 + d)) << 8) + n0) = val;
            }
        }
    } else if (MODE == MODE_OUT) {
        float* smf = (float*)sm;
#pragma unroll
        for (int half = 0; half < 2; ++half) {
            if (wr == half) {
#pragma unroll
                for (int mt = 0; mt < 4; ++mt) {
#pragma unroll
                    for (int nt = 0; nt < 4; ++nt) {
#pragma unroll
                        for (int r = 0; r < 4; ++r) {
                            int lrow = mt * 16 + (lane >> 4) * 4 + r;
                            int lcol = wc * 64 + nt * 16 + (lane & 15);
                            float v = acc[mt][nt][r] + p.bcat[1536 + tn * 128 + lcol];
                            int g = lcol >> 2;
                            smf[lrow * 128 + ((g ^ (lrow & 7)) << 2) + (lcol & 3)] = v;
                        }
                    }
                }
            }
            __syncthreads();
#pragma unroll
            for (int i = 0; i < 8; ++i) {
                int slot = i * 256 + t;
                int lrow = slot >> 5;
                int g = slot & 31;
                float4 val = *(const float4*)&smf[lrow * 128 + ((g ^ (lrow & 7)) << 2)];
                int row_g = tm * 128 + half * 64 + lrow;
                *(float4*)(p.out + ((size_t)row_g << 9) + tn * 128 + g * 4) = val;
            }
            __syncthreads();
        }
    } else {
        // KV / CTX: LDS-staged coalesced bf16 stores
#pragma unroll
        for (int mt = 0; mt < 4; ++mt) {
#pragma unroll
            for (int nt = 0; nt < 4; ++nt) {
#pragma unroll
                for (int r = 0; r < 4; ++r) {
                    int lrow = wr * 64 + mt * 16 + (lane >> 4) * 4 + r;
                    int lcol = wc * 64 + nt * 16 + (lane & 15);
                    float v = acc[mt][nt][r];
                    short sv;
                    if (MODE == MODE_KV) {
                        sv = f2bf(v);
                    } else { // MODE_CTX
                        int n = tm * 128 + lrow, d = tn * 128 + lcol;
                        float den = ((d < 128) ? p.dsb : p.dcb)[bhl * 256 + n] + 1e-6f;
                        float wgt = (d < 128) ? p.Ws[n * 128 + d] : p.Wc[n * 128 + (d - 128)];
                        sv = f2bf(v / den * wgt);
                    }
                    int g = lcol >> 3;
                    sm[lrow * 128 + ((g ^ (lrow & 7)) << 3) + (lcol & 7)] = sv;
                }
            }
        }
        __syncthreads();
#pragma unroll
        for (int i = 0; i < 8; ++i) {
            int slot = i * 256 + t;
            int lrow = slot >> 4;
            int g = slot & 15;
            bf16x8 val = *(const bf16x8*)&sm[lrow * 128 + ((g ^ (lrow & 7)) << 3)];
            int row = tm * 128 + lrow;
            int col0 = tn * 128 + g * 8;
            if (MODE == MODE_KV) {
                *(bf16x8*)(p.kvt + ((size_t)bhl << 16) + (row << 8) + col0) = val;
            } else {
                int bl = bhl >> 1, h = bhl & 1;
                *(bf16x8*)(p.Y + ((size_t)(bl * 256 + row) << 9) + h * 256 + col0) = val;
            }
        }
    }
}

__device__ __forceinline__ int xcd_swz(int b, int nwg) {
    int cpx = nwg >> 3;
    return (b & 7) * cpx + (b >> 3);
}

// ---------------- merged: cast (blocks 0..16383) + pack (16384..20479) ----------------
__global__ void k_cast_pack(const float* __restrict__ x, short* __restrict__ xb,
                            const float* __restrict__ Wq, const float* __restrict__ Wk,
                            const float* __restrict__ Wvs, const float* __restrict__ Wvc,
                            const float* __restrict__ Wp,
                            const float* __restrict__ bq, const float* __restrict__ bk,
                            const float* __restrict__ bvs, const float* __restrict__ bvc,
                            const float* __restrict__ bp, const float* __restrict__ power,
                            short* __restrict__ WcatT, float* __restrict__ bcat, float* __restrict__ pcol)
{
    int b = blockIdx.x;
    if (b < 16384) {
        int i = b * 256 + threadIdx.x;
        float4 v = ((const float4*)x)[i];
        short4 s;
        s.x = f2bf(v.x); s.y = f2bf(v.y); s.z = f2bf(v.z); s.w = f2bf(v.w);
        ((short4*)xb)[i] = s;
    } else {
        int i = (b - 16384) * 256 + threadIdx.x;      // 0 .. 2048*512-1
        int r = i >> 9, k = i & 511;
        float w;
        if (r < 512)       w = Wq[k * 512 + r];
        else if (r < 1024) w = Wk[k * 512 + (r - 512)];
        else if (r < 1536) {
            int rr = r - 1024; int h = rr >> 8; int d = rr & 255;
            w = (d < 128) ? Wvs[k * 256 + h * 128 + d] : Wvc[k * 256 + h * 128 + (d - 128)];
        } else             w = Wp[k * 512 + (r - 1536)];
        WcatT[i] = f2bf(w);

        if (i < 2048) {
            float bb;
            if (i < 512)       bb = bq[i];
            else if (i < 1024) bb = bk[i - 512];
            else if (i < 1536) {
                int rr = i - 1024; int h = rr >> 8; int d = rr & 255;
                bb = (d < 128) ? bvs[h * 128 + d] : bvc[h * 128 + (d - 128)];
            } else             bb = bp[i - 1536];
            bcat[i] = bb;
        }
        if (i < 512) pcol[i] = 1.0f + 3.0f / (1.0f + expf(-power[i]));
    }
}

// ---------------- merged: QK (blocks 0..2047) + VT (2048..3071) ----------------
__launch_bounds__(256, 4)
__global__ void k_qkvt(const short* __restrict__ xb, const short* __restrict__ Wcat, P p)
{
    __shared__ __align__(16) short sm[16384];
    int b = blockIdx.x;
    if (b < 2048) {
        gemm_body<MODE_QK>(sm, xcd_swz(b, 2048), xb, Wcat, 512, 8, p);
    } else {
        gemm_body<MODE_VT>(sm, xcd_swz(b - 2048, 1024), Wcat + 1024 * 512, xb, 512, 256, p);
    }
}

// ---------------- merged: KV (blocks 0..1023) + ksum (1024..17407) ----------------
__launch_bounds__(256, 4)
__global__ void k_kv_ksum(const short* __restrict__ vt, const short* __restrict__ ka,
                          float* __restrict__ kpsum, float* __restrict__ knsum, P p)
{
    __shared__ __align__(16) short sm[16384];
    int b = blockIdx.x;
    if (b < 1024) {
        gemm_body<MODE_KV>(sm, xcd_swz(b, 1024), vt, ka, 256, 2, p);
    } else {
        int gid = (b - 1024) * 256 + threadIdx.x;
        int gw = gid >> 6;
        int lane = gid & 63;
        short4 a4 = ((const short4*)(ka + ((size_t)gw << 8)))[lane];
        short aa[4] = {a4.x, a4.y, a4.z, a4.w};
        float sp = 0.f, sn = 0.f;
#pragma unroll
        for (int j = 0; j < 4; ++j) {
            float a = fabsf(bf2f(aa[j]));
            if (((unsigned short)aa[j] >> 15) == 0) sp += a; else sn += a;
        }
#pragma unroll
        for (int m = 1; m < 64; m <<= 1) { sp += __shfl_xor(sp, m, 64); sn += __shfl_xor(sn, m, 64); }
        if (lane == 0) { kpsum[gw] = sp; knsum[gw] = sn; }
    }
}

// ---------------- denominators ----------------
__global__ void k_denom(const short* __restrict__ qa,
                        const float* __restrict__ kpsum, const float* __restrict__ knsum,
                        float* __restrict__ dsb, float* __restrict__ dcb)
{
    int gid = blockIdx.x * 256 + threadIdx.x;
    int gw = gid >> 6;
    int lane = gid & 63;
    int bhl = gw >> 8;
    short4 q4 = ((const short4*)(qa + ((size_t)gw << 8)))[lane];
    float4 kp4 = ((const float4*)(kpsum + ((size_t)bhl << 8)))[lane];
    float4 kn4 = ((const float4*)(knsum + ((size_t)bhl << 8)))[lane];
    short qq[4] = {q4.x, q4.y, q4.z, q4.w};
    float kp[4] = {kp4.x, kp4.y, kp4.z, kp4.w};
    float kn[4] = {kn4.x, kn4.y, kn4.z, kn4.w};
    float ss = 0.f, sc = 0.f;
#pragma unroll
    for (int j = 0; j < 4; ++j) {
        float a = fabsf(bf2f(qq[j]));
        if (((unsigned short)qq[j] >> 15) == 0) { ss += a * kp[j]; sc += a * kn[j]; }
        else                                    { ss += a * kn[j]; sc += a * kp[j]; }
    }
#pragma unroll
    for (int m = 1; m < 64; m <<= 1) { ss += __shfl_xor(ss, m, 64); sc += __shfl_xor(sc, m, 64); }
    if (lane == 0) { dsb[gw] = ss; dcb[gw] = sc; }
}

// ---------------- CTX ----------------
__launch_bounds__(256, 4)
__global__ void k_ctx(const short* __restrict__ qa, const short* __restrict__ kvt, P p)
{
    __shared__ __align__(16) short sm[16384];
    gemm_body<MODE_CTX>(sm, xcd_swz(blockIdx.x, 1024), qa, kvt, 256, 2, p);
}

// ---------------- OUT ----------------
__launch_bounds__(256, 4)
__global__ void k_out(const short* __restrict__ Yb, const short* __restrict__ WpT, P p)
{
    __shared__ __align__(16) short sm[16384];
    gemm_body<MODE_OUT>(sm, xcd_swz(blockIdx.x, 1024), Yb, WpT, 512, 4, p);
}

extern "C" void kernel_launch(void* const* d_in, const int* in_sizes, int n_in,
                              void* d_out, int out_size, void* d_ws, size_t ws_size,
                              hipStream_t stream)
{
    const float* x     = (const float*)d_in[0];
    const float* Wq    = (const float*)d_in[1];
    const float* bq    = (const float*)d_in[2];
    const float* Wk    = (const float*)d_in[3];
    const float* bk    = (const float*)d_in[4];
    const float* Wvs   = (const float*)d_in[5];
    const float* bvs   = (const float*)d_in[6];
    const float* Wvc   = (const float*)d_in[7];
    const float* bvc   = (const float*)d_in[8];
    const float* power = (const float*)d_in[9];
    const float* Ws    = (const float*)d_in[10];
    const float* Wc    = (const float*)d_in[11];
    const float* Wp    = (const float*)d_in[12];
    const float* bp    = (const float*)d_in[13];
    (void)in_sizes; (void)n_in; (void)out_size; (void)ws_size;

    char* ws = (char*)d_ws;
    size_t off = 0;
    auto alloc = [&](size_t bytes) { void* pp = ws + off; off += (bytes + 255) & ~(size_t)255; return pp; };
    short* Wcat = (short*)alloc(2097152);           // [2048][512] bf16
    float* bcat = (float*)alloc(8192);
    float* pcol = (float*)alloc(2048);
    short* xb   = (short*)alloc(33554432);          // [32768][512] bf16; reused as Y by CTX
    short* qa   = (short*)alloc(33554432);          // [256 bhl][256 n][256] signed bf16
    short* ka   = (short*)alloc(33554432);
    short* vt   = (short*)alloc(33554432);          // [256 bhl][256 d][256 n]
    short* kvt  = (short*)alloc(33554432);
    float* kpsum= (float*)alloc(262144);
    float* knsum= (float*)alloc(262144);
    float* dsb  = (float*)alloc(262144);
    float* dcb  = (float*)alloc(262144);

    P p{};
    p.bcat = bcat; p.pcol = pcol;
    p.qa = qa; p.ka = ka;
    p.vt = vt; p.kvt = kvt;
    p.dsb = dsb; p.dcb = dcb; p.Ws = Ws; p.Wc = Wc;
    p.Y = xb; p.out = nullptr;                      // Y overwrites xb (safe: CTX after VT)

    // cast + pack (independent)
    k_cast_pack<<<20480, 256, 0, stream>>>(x, xb, Wq, Wk, Wvs, Wvc, Wp,
                                           bq, bk, bvs, bvc, bp, power, Wcat, bcat, pcol);

    // QK (M=32768,N=1024,K=512) + VT (transposed V projection) — independent
    k_qkvt<<<3072, 256, 0, stream>>>(xb, Wcat, p);

    // KV (kvT = vt * |ka|) + ksum — independent
    k_kv_ksum<<<17408, 256, 0, stream>>>(vt, ka, kpsum, knsum, p);

    // denominators
    k_denom<<<16384, 256, 0, stream>>>(qa, kpsum, knsum, dsb, dcb);

    // ctx -> Y (=xb)
    k_ctx<<<1024, 256, 0, stream>>>(qa, kvt, p);

    // out = Y @ Wp + bp (fp32)
    P po = p;
    po.out = (float*)d_out;
    k_out<<<1024, 256, 0, stream>>>(xb, Wcat + 1536 * 512, po);
}